// Round 7
// baseline (167.384 us; speedup 1.0000x reference)
//
#include <hip/hip_runtime.h>
#include <math.h>

#define BATCH 32
#define CH    3
#define H     512
#define W     512
#define KWIN  15
#define PAD   7
#define T2    16   // output rows per thread in pass 2

static __device__ __forceinline__ float2 min2(float2 a, float2 b) {
    float2 r;
    r.x = fminf(a.x, b.x);
    r.y = fminf(a.y, b.y);
    return r;
}
static __device__ __forceinline__ float4 min4(float4 a, float4 b) {
    float4 r;
    r.x = fminf(a.x, b.x); r.y = fminf(a.y, b.y);
    r.z = fminf(a.z, b.z); r.w = fminf(a.w, b.w);
    return r;
}

// Pass 1: channel-min + horizontal 15-min. One WAVE per row; lane L owns cols
// 8L..8L+7. No LDS, no barrier: the 15-window always covers the owning lane's
// whole segment, so out = min(suffix of left lane, lane total, prefix of right
// lane) with 14 shuffles/lane. Wave edge == row edge -> +inf fixup is exactly
// the torch -inf max-pool padding.
__global__ void dcp_p1(const float* __restrict__ I, float* __restrict__ tmp) {
    const int wid = (blockIdx.x << 2) + (threadIdx.x >> 6);  // global row id
    const int b   = wid >> 9;
    const int h   = wid & (H - 1);
    const int L   = threadIdx.x & 63;
    const int x   = L * 8;

    const float* p = I + ((size_t)b * CH * H + h) * W + x;
    const float4 a0 = *(const float4*)(p);
    const float4 a1 = *(const float4*)(p + 4);
    const float4 b0 = *(const float4*)(p + (size_t)H * W);
    const float4 b1 = *(const float4*)(p + (size_t)H * W + 4);
    const float4 c0 = *(const float4*)(p + (size_t)2 * H * W);
    const float4 c1 = *(const float4*)(p + (size_t)2 * H * W + 4);

    const float4 mlo = min4(min4(a0, b0), c0);   // cols x..x+3
    const float4 mhi = min4(min4(a1, b1), c1);   // cols x+4..x+7
    const float m0 = mlo.x, m1 = mlo.y, m2 = mlo.z, m3 = mlo.w;
    const float m4 = mhi.x, m5 = mhi.y, m6 = mhi.z, m7 = mhi.w;

    // prefix pr[i] = min(m0..mi), suffix sf[i] = min(mi..m7)
    float pr[8], sf[8];
    pr[0] = m0; pr[1] = fminf(pr[0], m1); pr[2] = fminf(pr[1], m2);
    pr[3] = fminf(pr[2], m3); pr[4] = fminf(pr[3], m4); pr[5] = fminf(pr[4], m5);
    pr[6] = fminf(pr[5], m6); pr[7] = fminf(pr[6], m7);
    sf[7] = m7; sf[6] = fminf(m6, sf[7]); sf[5] = fminf(m5, sf[6]);
    sf[4] = fminf(m4, sf[5]); sf[3] = fminf(m3, sf[4]); sf[2] = fminf(m2, sf[3]);
    sf[1] = fminf(m1, sf[2]); sf[0] = fminf(m0, sf[1]);
    const float M = pr[7];

    // sl[j] = suffix of lane L-1 starting at its idx j+1 (j=0..6)
    // pn[j] = prefix of lane L+1 up to its idx j      (j=0..6)
    float sl[7], pn[7];
    #pragma unroll
    for (int j = 0; j < 7; ++j) {
        sl[j] = __shfl_up(sf[j + 1], 1);
        pn[j] = __shfl_down(pr[j], 1);
    }
    if (L == 0) {
        #pragma unroll
        for (int j = 0; j < 7; ++j) sl[j] = INFINITY;
    }
    if (L == 63) {
        #pragma unroll
        for (int j = 0; j < 7; ++j) pn[j] = INFINITY;
    }

    // out col x+j: window covers suffix_{L-1}(j+1), all of lane L, prefix_{L+1}(j-1)
    float4 olo, ohi;
    olo.x = fminf(M, sl[0]);
    olo.y = fminf(M, fminf(sl[1], pn[0]));
    olo.z = fminf(M, fminf(sl[2], pn[1]));
    olo.w = fminf(M, fminf(sl[3], pn[2]));
    ohi.x = fminf(M, fminf(sl[4], pn[3]));
    ohi.y = fminf(M, fminf(sl[5], pn[4]));
    ohi.z = fminf(M, fminf(sl[6], pn[5]));
    ohi.w = fminf(M, pn[6]);

    float* q = tmp + ((size_t)b * H + h) * W + x;
    *(float4*)(q)     = olo;
    *(float4*)(q + 4) = ohi;
}

// Pass 2: vertical 15-min, van Herk over T2=16 output rows. Thread = 2 columns.
__global__ void dcp_p2(const float* __restrict__ tmp, float* __restrict__ out) {
    const int x  = threadIdx.x * 2;     // 256 threads cover all 512 cols
    const int y0 = blockIdx.x * T2;
    const int b  = blockIdx.y;

    const float* col = tmp + (size_t)b * H * W + x;
    float*       o   = out + (size_t)b * H * W + x;

    // Phase 1: seg1 = v[15..29] = rows y0+8 .. y0+22 (clamped; inf fixup last block)
    float2 vb[KWIN];
    #pragma unroll
    for (int j = 0; j < KWIN; ++j) {
        const int y = min(y0 + 8 + j, H - 1);
        vb[j] = *(const float2*)(col + (size_t)y * W);
    }
    if (y0 + 8 + KWIN - 1 >= H) {       // block-uniform (last y-block only)
        const float2 inf2 = make_float2(INFINITY, INFINITY);
        #pragma unroll
        for (int j = 0; j < KWIN; ++j)
            if (y0 + 8 + j >= H) vb[j] = inf2;
    }
    float2 P[KWIN];
    P[0] = vb[0];
    #pragma unroll
    for (int j = 1; j < KWIN; ++j) P[j] = min2(P[j - 1], vb[j]);
    *(float2*)(o + (size_t)(y0 + 15) * W) = P[14];   // o[15] = min(v[15..29])

    // Phase 2: seg0 = v[0..14] = rows y0-7 .. y0+7 (clamped; inf fixup first block)
    float2 va[KWIN];
    #pragma unroll
    for (int i = 0; i < KWIN; ++i) {
        const int y = max(y0 - PAD + i, 0);
        va[i] = *(const float2*)(col + (size_t)y * W);
    }
    if (y0 == 0) {                      // block-uniform
        const float2 inf2 = make_float2(INFINITY, INFINITY);
        #pragma unroll
        for (int i = 0; i < PAD; ++i) va[i] = inf2;
    }
    float2 run = va[14];
    *(float2*)(o + (size_t)(y0 + 14) * W) = min2(run, P[13]);
    #pragma unroll
    for (int r = 13; r >= 1; --r) {
        run = min2(run, va[r]);
        *(float2*)(o + (size_t)(y0 + r) * W) = min2(run, P[r - 1]);
    }
    run = min2(run, va[0]);
    *(float2*)(o + (size_t)y0 * W) = run;
}

extern "C" void kernel_launch(void* const* d_in, const int* in_sizes, int n_in,
                              void* d_out, int out_size, void* d_ws, size_t ws_size,
                              hipStream_t stream) {
    const float* I = (const float*)d_in[0];
    // d_in[1] is k == 15, hard-coded (KWIN/PAD)
    float* out = (float*)d_out;
    float* tmp = (float*)d_ws;          // 33.6 MB scratch

    dcp_p1<<<dim3((BATCH * H) / 4), dim3(256), 0, stream>>>(I, tmp);
    dcp_p2<<<dim3(H / T2, BATCH), dim3(256), 0, stream>>>(tmp, out);
}

// Round 8
// 163.683 us; speedup vs baseline: 1.0226x; 1.0226x over previous
//
#include <hip/hip_runtime.h>
#include <math.h>

#define BATCH 32
#define CH    3
#define H     512
#define W     512
#define KWIN  15
#define PAD   7
#define TH    16                // output rows per block
#define NR    (TH + KWIN - 1)   // 30 h-min rows per tile

static __device__ __forceinline__ float2 min2(float2 a, float2 b) {
    float2 r;
    r.x = fminf(a.x, b.x);
    r.y = fminf(a.y, b.y);
    return r;
}
static __device__ __forceinline__ float4 min4(float4 a, float4 b) {
    float4 r;
    r.x = fminf(a.x, b.x); r.y = fminf(a.y, b.y);
    r.z = fminf(a.z, b.z); r.w = fminf(a.w, b.w);
    return r;
}

// Fused dark-channel + 15x15 min-pool, single barrier.
// Phase 1: wave-per-row channel-min + horizontal 15-min (R7 shuffle pattern,
//   no LDS, loads unconditional via clamped row index -> full MLP), results
//   into hm[30][512]. Phase 2: per-column van Herk vertical 15-min from LDS
//   (b64 lane-stride-8B reads: the measured conflict-free pattern).
// No __launch_bounds__ (hints produced 20-VGPR serialization / 64-VGPR spills).
__global__ void dcp_fused5(const float* __restrict__ I, float* __restrict__ out) {
    const int b    = blockIdx.y;
    const int y0   = blockIdx.x * TH;
    const int tid  = threadIdx.x;
    const int wave = tid >> 6;
    const int L    = tid & 63;
    const int x    = L * 8;                  // lane's 8 columns (phase 1)

    __shared__ float hm[NR][W];              // 60 KB: h-min rows y0-7 .. y0+22

    const float* base = I + (size_t)b * CH * H * W;

    // ---- Phase 1: h-min rows i = wave, wave+4, ... (wave-uniform guard) ----
    #pragma unroll
    for (int ii = 0; ii < (NR + 3) / 4; ++ii) {
        const int i = wave + ii * 4;
        if (i < NR) {
            const int y  = y0 - PAD + i;
            const int yc = min(max(y, 0), H - 1);
            const float* p = base + (size_t)yc * W + x;
            const float4 a0 = *(const float4*)(p);
            const float4 a1 = *(const float4*)(p + 4);
            const float4 b0 = *(const float4*)(p + (size_t)H * W);
            const float4 b1 = *(const float4*)(p + (size_t)H * W + 4);
            const float4 c0 = *(const float4*)(p + (size_t)2 * H * W);
            const float4 c1 = *(const float4*)(p + (size_t)2 * H * W + 4);
            float4 mlo = min4(min4(a0, b0), c0);   // cols x..x+3
            float4 mhi = min4(min4(a1, b1), c1);   // cols x+4..x+7
            if (y < 0 || y >= H) {                 // wave-uniform: pad row = +inf
                mlo = make_float4(INFINITY, INFINITY, INFINITY, INFINITY);
                mhi = mlo;
            }
            const float m0 = mlo.x, m1 = mlo.y, m2 = mlo.z, m3 = mlo.w;
            const float m4 = mhi.x, m5 = mhi.y, m6 = mhi.z, m7 = mhi.w;

            float pr[8], sf[8];
            pr[0] = m0;            pr[1] = fminf(pr[0], m1);
            pr[2] = fminf(pr[1], m2); pr[3] = fminf(pr[2], m3);
            pr[4] = fminf(pr[3], m4); pr[5] = fminf(pr[4], m5);
            pr[6] = fminf(pr[5], m6); pr[7] = fminf(pr[6], m7);
            sf[7] = m7;            sf[6] = fminf(m6, sf[7]);
            sf[5] = fminf(m5, sf[6]); sf[4] = fminf(m4, sf[5]);
            sf[3] = fminf(m3, sf[4]); sf[2] = fminf(m2, sf[3]);
            sf[1] = fminf(m1, sf[2]); sf[0] = fminf(m0, sf[1]);
            const float M = pr[7];

            float sl[7], pn[7];
            #pragma unroll
            for (int j = 0; j < 7; ++j) {
                sl[j] = __shfl_up(sf[j + 1], 1);   // suffix of lane L-1 from idx j+1
                pn[j] = __shfl_down(pr[j], 1);     // prefix of lane L+1 to idx j
            }
            if (L == 0) {
                #pragma unroll
                for (int j = 0; j < 7; ++j) sl[j] = INFINITY;
            }
            if (L == 63) {
                #pragma unroll
                for (int j = 0; j < 7; ++j) pn[j] = INFINITY;
            }

            float4 olo, ohi;
            olo.x = fminf(M, sl[0]);
            olo.y = fminf(M, fminf(sl[1], pn[0]));
            olo.z = fminf(M, fminf(sl[2], pn[1]));
            olo.w = fminf(M, fminf(sl[3], pn[2]));
            ohi.x = fminf(M, fminf(sl[4], pn[3]));
            ohi.y = fminf(M, fminf(sl[5], pn[4]));
            ohi.z = fminf(M, fminf(sl[6], pn[5]));
            ohi.w = fminf(M, pn[6]);

            *(float4*)&hm[i][x]     = olo;
            *(float4*)&hm[i][x + 4] = ohi;
        }
    }
    __syncthreads();                         // the only barrier

    // ---- Phase 2: vertical 15-min via van Herk; thread = 2 cols, 16 rows ----
    const int xc = tid * 2;
    float*    o  = out + ((size_t)b * H + y0) * W + xc;

    float2 P[KWIN];                          // P[j] = min(hm rows 15..15+j)
    P[0] = *(const float2*)&hm[KWIN][xc];
    #pragma unroll
    for (int j = 1; j < KWIN; ++j)
        P[j] = min2(P[j - 1], *(const float2*)&hm[KWIN + j][xc]);
    *(float2*)(o + (size_t)15 * W) = P[14];  // out row y0+15 = rows 15..29

    float2 run = *(const float2*)&hm[14][xc];
    *(float2*)(o + (size_t)14 * W) = min2(run, P[13]);
    #pragma unroll
    for (int r = 13; r >= 1; --r) {
        run = min2(run, *(const float2*)&hm[r][xc]);
        *(float2*)(o + (size_t)r * W) = min2(run, P[r - 1]);
    }
    run = min2(run, *(const float2*)&hm[0][xc]);
    *(float2*)(o) = run;
}

extern "C" void kernel_launch(void* const* d_in, const int* in_sizes, int n_in,
                              void* d_out, int out_size, void* d_ws, size_t ws_size,
                              hipStream_t stream) {
    const float* I = (const float*)d_in[0];
    // d_in[1] is k == 15, hard-coded (KWIN/PAD)
    float* out = (float*)d_out;
    dcp_fused5<<<dim3(H / TH, BATCH), dim3(256), 0, stream>>>(I, out);
}